// Round 12
// baseline (366.555 us; speedup 1.0000x reference)
//
// r12: attention KBLK=128 (half the barriers, 48KB LDS @ 3/CU) + up-proj TN=192 (512 blocks, 2/CU exact)
#include <hip/hip_runtime.h>
#include <hip/hip_bf16.h>

typedef __bf16 bf16;
typedef __bf16 v8bf __attribute__((ext_vector_type(8)));
typedef __bf16 v4bf __attribute__((ext_vector_type(4)));
typedef float  v4f  __attribute__((ext_vector_type(4)));

#define DEVI __device__ __forceinline__

constexpr int Bc   = 4;
constexpr int Tc   = 2048;
constexpr int Dc   = 768;
constexpr int Hc   = 12;
constexpr int HDc  = 64;
constexpr int MLPc = 3072;
constexpr int QKVc = 2304;    // 3*D
constexpr int BTc  = Bc * Tc; // 8192 rows

DEVI float b2f(bf16 x) { return (float)x; }
DEVI bf16  f2b(float x) { return (bf16)x; }

// async global->LDS, 16B per lane; lds dest = wave-uniform base + lane*16
#define GLDS(gp, lp) __builtin_amdgcn_global_load_lds( \
    (const __attribute__((address_space(1))) void*)(gp), \
    (__attribute__((address_space(3))) void*)(lp), 16, 0, 0)

// ---------------------------------------------------------------- LayerNorm (fp32 in, bf16 out)
// + folded fp32->bf16 weight conversion: blocks >= BTc convert (cs0->cd0 | cs1->cd1)
__global__ __launch_bounds__(256) void ln_kernel(
    const float* __restrict__ x, const float* __restrict__ g,
    const float* __restrict__ bt, bf16* __restrict__ out,
    const float* __restrict__ cs0, bf16* __restrict__ cd0, int n0c,
    const float* __restrict__ cs1, bf16* __restrict__ cd1)
{
    const int blk = blockIdx.x;
    const int t = threadIdx.x;
    if (blk >= BTc) {                 // weight-conversion tail blocks
        int i = (blk - BTc) * 256 + t;
        const float* s; bf16* d; int j;
        if (i < n0c) { s = cs0; d = cd0; j = i; }
        else         { s = cs1; d = cd1; j = i - n0c; }
        float4 v = ((const float4*)s)[j];
        v4bf o = { f2b(v.x), f2b(v.y), f2b(v.z), f2b(v.w) };
        ((v4bf*)d)[j] = o;
        return;
    }
    const float* xr = x + (size_t)blk * Dc;
    float v[3];
    v[0] = xr[t];
    v[1] = xr[t + 256];
    v[2] = xr[t + 512];
    float s = v[0] + v[1] + v[2];
    float s2 = v[0]*v[0] + v[1]*v[1] + v[2]*v[2];
    #pragma unroll
    for (int off = 32; off > 0; off >>= 1) {
        s  += __shfl_down(s, off);
        s2 += __shfl_down(s2, off);
    }
    __shared__ float red[8];
    const int wave = t >> 6, lane = t & 63;
    if (lane == 0) { red[wave] = s; red[4 + wave] = s2; }
    __syncthreads();
    s  = red[0] + red[1] + red[2] + red[3];
    s2 = red[4] + red[5] + red[6] + red[7];
    const float mean = s * (1.0f / Dc);
    const float var  = s2 * (1.0f / Dc) - mean * mean;
    const float rstd = rsqrtf(var + 1e-5f);
    bf16* orow = out + (size_t)blk * Dc;
    #pragma unroll
    for (int i = 0; i < 3; i++) {
        int c = t + i * 256;
        orow[c] = f2b((v[i] - mean) * rstd * g[c] + bt[c]);
    }
}

// ---------------------------------------------------------------- GEMM (C = A @ B^T + bias, fused epilogues)
// TN = 192 (4 waves 2Mx2N of 64x96, 48 MFMA/K-step/wave): qkv grid 12x64 =
//   768 = exact 3/CU fill; up-proj grid 8x64 = 512 = exact 2/CU fill.
// TN = 64 (4 waves of 32x64) + BK=128 for out/down (grid 12x64 = 768 exact).
// Single-buffered __syncthreads loop (dbuf and 256^2 both measured worse:
// occupancy/fill beats source-level pipelining at these small-K shapes).
// XCD mapping m-innermost: B panel streams through each XCD exactly once.
// EPI_QKV: split-store Q|K|Vt; Q pre-scaled by log2(e)/8.
enum { EPI_QKV = 0, EPI_GELU_BF16 = 1, EPI_RESID_F32 = 2, EPI_ACC_F32 = 3 };

template <int EPI, int TN, int BK>
__global__ __launch_bounds__(256, 3) void gemm_bt(
    const bf16* __restrict__ A, const bf16* __restrict__ Bw,
    const float* __restrict__ bias,
    bf16* __restrict__ Cb, float* __restrict__ Cf,
    const float* __restrict__ resf,
    int M, int N, int K, int lda, int ldb)
{
    constexpr int MI = (TN == 64) ? 2 : 4;       // 16-row blocks per wave (m)
    constexpr int NI = (TN == 192) ? 6 : 4;      // 16-col blocks per wave (n)
    constexpr int CH = BK / 8;                   // 16B chunks per tile row
    __shared__ __align__(16) bf16 sA[128 * BK];
    __shared__ __align__(16) bf16 sB[TN * BK];
    const int t = threadIdx.x, wave = t >> 6, lane = t & 63;
    const int moff = (TN == 64) ? wave * 32 : (wave & 1) * 64;
    const int noff = (TN == 64) ? 0 : (wave >> 1) * (NI * 16);
    // XCD stripe swizzle, m innermost (ny divisible by 8 for all our shapes)
    const int nx = gridDim.x, ny = gridDim.y;
    const int nym = ny >> 3;                     // m-tiles per XCD
    const int bid = blockIdx.y * nx + blockIdx.x;
    const int xcd = bid & 7, kk = bid >> 3;
    const int m0 = (xcd * nym + kk % nym) * 128;
    const int n0 = (kk / nym) * TN;
    const bf16* Ag = A + (size_t)m0 * lda;
    const bf16* Bg = Bw + (size_t)n0 * ldb;

    v4f acc[MI][NI];
    #pragma unroll
    for (int i = 0; i < MI; i++)
        #pragma unroll
        for (int j = 0; j < NI; j++) acc[i][j] = (v4f)(0.0f);

    for (int k0 = 0; k0 < K; k0 += BK) {
        // stage with XOR swizzle: LDS chunk l holds global chunk ((l&7)^(r&7))|(l&~7)
        #pragma unroll
        for (int i = 0; i < (128 * CH) / 256; i++) {
            int c = i * 256 + t;
            int r = c / CH, l0 = c % CH;
            int j = ((l0 & 7) ^ (r & 7)) | (l0 & ~7);
            GLDS(Ag + (size_t)r * lda + k0 + j * 8,
                 &sA[(i * 256 + wave * 64) * 8]);
        }
        #pragma unroll
        for (int i = 0; i < (TN * CH) / 256; i++) {
            int c = i * 256 + t;
            int r = c / CH, l0 = c % CH;
            int j = ((l0 & 7) ^ (r & 7)) | (l0 & ~7);
            GLDS(Bg + (size_t)r * ldb + k0 + j * 8,
                 &sB[(i * 256 + wave * 64) * 8]);
        }
        __syncthreads();
        #pragma unroll
        for (int ks = 0; ks < BK / 32; ks++) {
            const int rq = lane >> 4, rl = lane & 15;
            const int q = ks * 4 + rq;
            v8bf a[MI], b[NI];
            #pragma unroll
            for (int mi = 0; mi < MI; mi++) {
                const int row = moff + mi * 16 + rl;
                const int l = ((q & 7) ^ (row & 7)) | (q & ~7);
                a[mi] = *(const v8bf*)&sA[row * BK + l * 8];
            }
            #pragma unroll
            for (int ni = 0; ni < NI; ni++) {
                const int row = noff + ni * 16 + rl;
                const int l = ((q & 7) ^ (row & 7)) | (q & ~7);
                b[ni] = *(const v8bf*)&sB[row * BK + l * 8];
            }
            #pragma unroll
            for (int mi = 0; mi < MI; mi++)
                #pragma unroll
                for (int ni = 0; ni < NI; ni++)
                    acc[mi][ni] = __builtin_amdgcn_mfma_f32_16x16x32_bf16(
                        a[mi], b[ni], acc[mi][ni], 0, 0, 0);
        }
        __syncthreads();
    }

    const int rq = lane >> 4, cn = lane & 15;
    #pragma unroll
    for (int mi = 0; mi < MI; mi++)
        #pragma unroll
        for (int ni = 0; ni < NI; ni++) {
            const int col = n0 + noff + ni * 16 + cn;
            const float bv = bias ? bias[col] : 0.0f;
            if constexpr (EPI == EPI_QKV) {
                const int row0 = m0 + moff + mi * 16 + rq * 4;
                if (col < 2 * Dc) {
                    bf16* dst = Cb + (col < Dc ? 0 : (size_t)BTc * Dc);
                    const int cadj = col < Dc ? col : col - Dc;
                    const float qs = (col < Dc) ? 0.18033688011112042f : 1.0f;
                    #pragma unroll
                    for (int r = 0; r < 4; r++)
                        dst[(size_t)(row0 + r) * Dc + cadj] = f2b((acc[mi][ni][r] + bv) * qs);
                } else {
                    const int vcol = col - 2 * Dc;
                    const int hh = vcol >> 6, hd = vcol & 63;
                    const int bb = row0 >> 11, t0 = row0 & 2047;
                    v4bf pk;
                    #pragma unroll
                    for (int r = 0; r < 4; r++) pk[r] = f2b(acc[mi][ni][r] + bv);
                    *(v4bf*)(Cb + 2 * (size_t)BTc * Dc +
                             (((size_t)bb * Hc + hh) * HDc + hd) * Tc + t0) = pk;
                }
            } else {
                #pragma unroll
                for (int r = 0; r < 4; r++) {
                    const int row = m0 + moff + mi * 16 + rq * 4 + r;
                    const size_t idx = (size_t)row * N + col;
                    float vv = acc[mi][ni][r] + bv;
                    if constexpr (EPI == EPI_GELU_BF16) {
                        Cb[idx] = f2b(0.5f * vv * (1.0f + erff(vv * 0.70710678118f)));
                    } else if constexpr (EPI == EPI_RESID_F32) {
                        Cf[idx] = vv + resf[idx];
                    } else {  // EPI_ACC_F32: sequential RMW accumulate
                        Cf[idx] = vv + Cf[idx];
                    }
                }
            }
        }
}

// ---------------------------------------------------------------- Banded flash attention, v6
// v5 core (LDS-staged K/V, 32-row q-strips, transposed-S b64 P-writes,
// l via ones-MFMA, no exp clamp) + r12: KBLK=128 phases -- stage K[128x64]
// + V[64x128] per phase (16+16KB; +sP = 48KB, still 3 blocks/CU) and run
// both 64-key halves between ONE barrier pair. Halves the __syncthreads
// count (each drains vmcnt(0) -- the structural stall) at identical staging
// volume and identical MFMA/exp work.
__global__ __launch_bounds__(256, 3) void attn_kernel(
    const bf16* __restrict__ Qb, const bf16* __restrict__ Kb,
    const bf16* __restrict__ Vt, bf16* __restrict__ o,
    const int* __restrict__ winp)
{
    const int bh = blockIdx.x, qt = blockIdx.y;
    const int b = bh / Hc, h = bh % Hc;
    const int q0 = qt * 128;
    const int win = *winp;
    const int t = threadIdx.x, wave = t >> 6, lane = t & 63;
    const int rq = lane >> 4, cn = lane & 15;
    const int qw0 = q0 + wave * 32;              // this wave's 32-row q-strip

    __shared__ __align__(16) bf16 sK[128 * 64];  // 128 keys x 64 d
    __shared__ __align__(16) bf16 sV[64 * 128];  // 64 hd x 128 keys
    __shared__ __align__(16) bf16 sP[4][32 * 64];
    bf16* const sPw = &sP[wave][0];
    const int swz = (cn & 7) << 1;               // XOR on 8B-chunk index

    const bf16* qp  = Qb + ((size_t)b * Tc) * Dc + h * HDc;
    const bf16* kp  = Kb + ((size_t)b * Tc) * Dc + h * HDc;
    const bf16* vtp = Vt + (size_t)bh * HDc * Tc;

    // Q fragments (B-operand: col=q=cn within tile mi, k = ks*32+rq*8)
    v8bf qf[2][2];
    #pragma unroll
    for (int ks = 0; ks < 2; ks++)
        #pragma unroll
        for (int mi = 0; mi < 2; mi++)
            qf[ks][mi] = *(const v8bf*)(qp + (size_t)(qw0 + mi * 16 + cn) * Dc
                                        + ks * 32 + rq * 8);

    v4f acc_o[2][4], acc_l[2];
    #pragma unroll
    for (int mi = 0; mi < 2; mi++) {
        acc_l[mi] = (v4f)(0.0f);
        #pragma unroll
        for (int nh = 0; nh < 4; nh++) acc_o[mi][nh] = (v4f)(0.0f);
    }
    v8bf vones;
    #pragma unroll
    for (int j = 0; j < 8; j++) vones[j] = f2b(1.0f);

    // block band; per-wave valid range
    const int wlo = max(0, qw0 - win), whi = min(Tc - 1, qw0 + 31 + win);
    const int klo = max(0, q0 - win) & ~127;     // 128-aligned phase base
    const int khi = min(Tc - 1, q0 + 127 + win);

    for (int kb0 = klo; kb0 <= khi; kb0 += 128) {
        // cooperative stage: K rows [kb0..+128) x 64d (4x16B/thread),
        // V^T rows [0..64) x keys [kb0..+128) (4x16B/thread).
        // K swizzle: chunk j = (c&7)^(r&7) (8 chunks/row).
        // V swizzle: 16 chunks/row -> j = ((l&7)^(r&7))|(l&8) (bit 3 kept).
        #pragma unroll
        for (int i = 0; i < 4; i++) {
            int c = i * 256 + t;
            int rk = c >> 3, jk = (c & 7) ^ (rk & 7);
            GLDS(kp + (size_t)(kb0 + rk) * Dc + jk * 8,
                 &sK[(i * 256 + wave * 64) * 8]);
            int rv = c >> 4, lv = c & 15;
            int jv = ((lv & 7) ^ (rv & 7)) | (lv & 8);
            GLDS(vtp + (size_t)rv * Tc + kb0 + jv * 8,
                 &sV[(i * 256 + wave * 64) * 8]);
        }
        __syncthreads();

        #pragma unroll
        for (int half = 0; half < 2; half++) {
            const int kb = kb0 + half * 64;
            if (kb + 63 >= wlo && kb <= whi) {
                // S^T = K Q^T : sf[k4][mi], row k = kb+k4*16+rq*4+r, col q = mi*16+cn
                v4f sf[4][2];
                #pragma unroll
                for (int k4 = 0; k4 < 4; k4++)
                    #pragma unroll
                    for (int mi = 0; mi < 2; mi++) sf[k4][mi] = (v4f)(0.0f);
                #pragma unroll
                for (int ks = 0; ks < 2; ks++) {
                    v8bf kf[4];
                    #pragma unroll
                    for (int k4 = 0; k4 < 4; k4++) {
                        const int row = half * 64 + k4 * 16 + cn;
                        kf[k4] = *(const v8bf*)&sK[row * 64
                                                  + ((ks * 4 + rq) ^ (row & 7)) * 8];
                    }
                    #pragma unroll
                    for (int k4 = 0; k4 < 4; k4++)
                        #pragma unroll
                        for (int mi = 0; mi < 2; mi++)
                            sf[k4][mi] = __builtin_amdgcn_mfma_f32_16x16x32_bf16(
                                kf[k4], qf[ks][mi], sf[k4][mi], 0, 0, 0);
                }

                // p = exp2(sT); band mask only on edge halves
                const bool need_mask = (kb + 63 - qw0 > win) || (qw0 + 31 - kb > win);
                #pragma unroll
                for (int k4 = 0; k4 < 4; k4++)
                    #pragma unroll
                    for (int mi = 0; mi < 2; mi++) {
                        v4bf pk;
                        #pragma unroll
                        for (int r = 0; r < 4; r++) {
                            float tt = sf[k4][mi][r];
                            if (need_mask) {
                                int ki = kb + k4 * 16 + rq * 4 + r;
                                int qi = qw0 + mi * 16 + cn;
                                int dd = qi - ki; dd = dd < 0 ? -dd : dd;
                                tt = (dd > win) ? -INFINITY : tt;
                            }
                            pk[r] = f2b(exp2f(tt));   // masked -> 0
                        }
                        *(v4bf*)&sPw[(mi * 16 + cn) * 64
                                     + (((k4 * 4 + rq) ^ swz) << 2)] = pk;
                    }

                // O += P V ; l += P 1  (A: row q = mi*16+cn; B from sV / ones)
                #pragma unroll
                for (int ks = 0; ks < 2; ks++) {
                    v8bf pa[2], vf[4];
                    #pragma unroll
                    for (int mi = 0; mi < 2; mi++)
                        pa[mi] = *(const v8bf*)&sPw[(mi * 16 + cn) * 64
                                                    + (((ks * 8 + rq * 2) ^ swz) << 2)];
                    #pragma unroll
                    for (int nh = 0; nh < 4; nh++) {
                        const int row = nh * 16 + cn;
                        const int lv = half * 8 + ks * 4 + rq;
                        const int jv = ((lv & 7) ^ (row & 7)) | (lv & 8);
                        vf[nh] = *(const v8bf*)&sV[row * 128 + jv * 8];
                    }
                    #pragma unroll
                    for (int mi = 0; mi < 2; mi++)
                        acc_l[mi] = __builtin_amdgcn_mfma_f32_16x16x32_bf16(
                            pa[mi], vones, acc_l[mi], 0, 0, 0);
                    #pragma unroll
                    for (int mi = 0; mi < 2; mi++)
                        #pragma unroll
                        for (int nh = 0; nh < 4; nh++)
                            acc_o[mi][nh] = __builtin_amdgcn_mfma_f32_16x16x32_bf16(
                                pa[mi], vf[nh], acc_o[mi][nh], 0, 0, 0);
                }
            }
        }
        __syncthreads();
    }

    // epilogue: normalize + store; l for row rq*4+r is acc_l[mi][r]
    bf16* ob = o + ((size_t)b * Tc + qw0) * Dc + h * HDc;
    #pragma unroll
    for (int mi = 0; mi < 2; mi++)
        #pragma unroll
        for (int r = 0; r < 4; r++) {
            const float invl = 1.0f / acc_l[mi][r];  // diag in band -> l > 0
            #pragma unroll
            for (int nh = 0; nh < 4; nh++)
                ob[(size_t)(mi * 16 + rq * 4 + r) * Dc + nh * 16 + cn] =
                    f2b(acc_o[mi][nh][r] * invl);
        }
}

// ---------------------------------------------------------------- launch
extern "C" void kernel_launch(void* const* d_in, const int* in_sizes, int n_in,
                              void* d_out, int out_size, void* d_ws, size_t ws_size,
                              hipStream_t stream)
{
    const float* x     = (const float*)d_in[0];
    const float* inw   = (const float*)d_in[1];
    const float* inb   = (const float*)d_in[2];
    const float* outw  = (const float*)d_in[3];
    const float* outb  = (const float*)d_in[4];
    const float* w1    = (const float*)d_in[5];
    const float* b1    = (const float*)d_in[6];
    const float* w2    = (const float*)d_in[7];
    const float* b2    = (const float*)d_in[8];
    const float* ln1g  = (const float*)d_in[9];
    const float* ln1b  = (const float*)d_in[10];
    const float* ln2g  = (const float*)d_in[11];
    const float* ln2b  = (const float*)d_in[12];
    const int*   winp  = (const int*)d_in[13];
    float* out = (float*)d_out;   // fp32 [8192][768]; holds x1 mid-pipeline

    // Workspace (55.05 MB needed; >=62.9 MB proven available)
    char* ws = (char*)d_ws;
    constexpr size_t A_OFF   = 0;
    constexpr size_t QKV_OFF = (size_t)BTc * Dc * 2;                   // 12582912
    constexpr size_t WA_OFF  = QKV_OFF + 3 * (size_t)BTc * Dc * 2;     // 50331648
    constexpr size_t WS_NEED = WA_OFF + (size_t)(QKVc + Dc) * Dc * 2;  // 55050240
    if (ws_size < WS_NEED) return;

    bf16*  xn     = (bf16*)(ws + A_OFF);            // xn1 / obuf / xn2
    bf16*  qkvb   = (bf16*)(ws + QKV_OFF);          // Qb|Kb|Vt triple
    bf16*  Qb     = qkvb;
    bf16*  Kb     = qkvb + (size_t)BTc * Dc;
    bf16*  Vt     = qkvb + 2 * (size_t)BTc * Dc;
    bf16*  hbuf   = (bf16*)(ws + QKV_OFF);          // phase B: [8192][1536] bf16
    bf16*  wmlp   = (bf16*)(ws + QKV_OFF + (size_t)BTc * (2 * Dc) * 2);
    bf16*  w1_b   = wmlp;
    bf16*  w2_b   = wmlp + (size_t)MLPc * Dc;
    bf16*  wqkv_b = (bf16*)(ws + WA_OFF);
    bf16*  wout_b = wqkv_b + (size_t)QKVc * Dc;

    constexpr int HALF = MLPc / 2;  // 1536 cols per MLP half (N-split)
    constexpr int NQKV4 = QKVc * Dc / 4, NOUT4 = Dc * Dc / 4;
    constexpr int NW14  = MLPc * Dc / 4, NW24  = Dc * MLPc / 4;
    constexpr int CVA_BLKS = (NQKV4 + NOUT4) / 256;  // 2304
    constexpr int CVB_BLKS = (NW14 + NW24) / 256;    // 4608

    // 1. LN1 (fp32 x -> bf16 xn) + folded phase-A weight conversion
    ln_kernel<<<BTc + CVA_BLKS, 256, 0, stream>>>(
        x, ln1g, ln1b, xn, inw, wqkv_b, NQKV4, outw, wout_b);
    // 2. qkv GEMM, TN=192: grid 12x64 = 768 = exact 3/CU fill
    gemm_bt<EPI_QKV, 192, 64><<<dim3(QKVc / 192, BTc / 128), 256, 0, stream>>>(
        xn, wqkv_b, inb, qkvb, nullptr, nullptr, BTc, QKVc, Dc, Dc, Dc);
    // 3. banded attention (KBLK=128 dbuf-free phases) -> obuf (= xn)
    attn_kernel<<<dim3(Bc * Hc, Tc / 128), 256, 0, stream>>>(Qb, Kb, Vt, xn, winp);
    // 4. out(x1) = x + obuf @ out_w^T + out_b  (fp32, fused residual; BK=128;
    //    grid 12x64 = 768 blocks = exact 3/CU fill)
    gemm_bt<EPI_RESID_F32, 64, 128><<<dim3(Dc / 64, BTc / 128), 256, 0, stream>>>(
        xn, wout_b, outb, nullptr, out, x, BTc, Dc, Dc, Dc, Dc);
    // 5. LN2 (d_out fp32 -> bf16 xn2) + folded phase-B weight conversion
    ln_kernel<<<BTc + CVB_BLKS, 256, 0, stream>>>(
        out, ln2g, ln2b, xn, w1, w1_b, NW14, w2, w2_b);

    // 6/7. MLP in two 1536-wide N-halves. Up: TN=192 -> grid 8x64 = 512 =
    // exact 2/CU fill, 48 MFMA/barrier (r12 experiment; attribute via profile).
    // Down: K=1536, BK=128, sequential RMW accumulate onto d_out (768 blocks).
    for (int c = 0; c < 2; c++) {
        const bf16* w1c = w1_b + (size_t)c * HALF * Dc;   // rows [c*1536, ..)
        const bf16* w2c = w2_b + (size_t)c * HALF;        // cols [c*1536, ..)
        gemm_bt<EPI_GELU_BF16, 192, 64><<<dim3(HALF / 192, BTc / 128), 256, 0, stream>>>(
            xn, w1c, b1 + c * HALF, hbuf, nullptr, nullptr, BTc, HALF, Dc, Dc, Dc);
        gemm_bt<EPI_ACC_F32, 64, 128><<<dim3(Dc / 64, BTc / 128), 256, 0, stream>>>(
            hbuf, w2c, (c == 0) ? b2 : nullptr, nullptr, out, nullptr,
            BTc, Dc, HALF, HALF, MLPc);
    }
}

// Round 13
// 345.490 us; speedup vs baseline: 1.0610x; 1.0610x over previous
//
// r13: bisection — revert up-proj to TN=128 (r11 proven), keep attention KBLK=128
#include <hip/hip_runtime.h>
#include <hip/hip_bf16.h>

typedef __bf16 bf16;
typedef __bf16 v8bf __attribute__((ext_vector_type(8)));
typedef __bf16 v4bf __attribute__((ext_vector_type(4)));
typedef float  v4f  __attribute__((ext_vector_type(4)));

#define DEVI __device__ __forceinline__

constexpr int Bc   = 4;
constexpr int Tc   = 2048;
constexpr int Dc   = 768;
constexpr int Hc   = 12;
constexpr int HDc  = 64;
constexpr int MLPc = 3072;
constexpr int QKVc = 2304;    // 3*D
constexpr int BTc  = Bc * Tc; // 8192 rows

DEVI float b2f(bf16 x) { return (float)x; }
DEVI bf16  f2b(float x) { return (bf16)x; }

// async global->LDS, 16B per lane; lds dest = wave-uniform base + lane*16
#define GLDS(gp, lp) __builtin_amdgcn_global_load_lds( \
    (const __attribute__((address_space(1))) void*)(gp), \
    (__attribute__((address_space(3))) void*)(lp), 16, 0, 0)

// ---------------------------------------------------------------- LayerNorm (fp32 in, bf16 out)
// + folded fp32->bf16 weight conversion: blocks >= BTc convert (cs0->cd0 | cs1->cd1)
__global__ __launch_bounds__(256) void ln_kernel(
    const float* __restrict__ x, const float* __restrict__ g,
    const float* __restrict__ bt, bf16* __restrict__ out,
    const float* __restrict__ cs0, bf16* __restrict__ cd0, int n0c,
    const float* __restrict__ cs1, bf16* __restrict__ cd1)
{
    const int blk = blockIdx.x;
    const int t = threadIdx.x;
    if (blk >= BTc) {                 // weight-conversion tail blocks
        int i = (blk - BTc) * 256 + t;
        const float* s; bf16* d; int j;
        if (i < n0c) { s = cs0; d = cd0; j = i; }
        else         { s = cs1; d = cd1; j = i - n0c; }
        float4 v = ((const float4*)s)[j];
        v4bf o = { f2b(v.x), f2b(v.y), f2b(v.z), f2b(v.w) };
        ((v4bf*)d)[j] = o;
        return;
    }
    const float* xr = x + (size_t)blk * Dc;
    float v[3];
    v[0] = xr[t];
    v[1] = xr[t + 256];
    v[2] = xr[t + 512];
    float s = v[0] + v[1] + v[2];
    float s2 = v[0]*v[0] + v[1]*v[1] + v[2]*v[2];
    #pragma unroll
    for (int off = 32; off > 0; off >>= 1) {
        s  += __shfl_down(s, off);
        s2 += __shfl_down(s2, off);
    }
    __shared__ float red[8];
    const int wave = t >> 6, lane = t & 63;
    if (lane == 0) { red[wave] = s; red[4 + wave] = s2; }
    __syncthreads();
    s  = red[0] + red[1] + red[2] + red[3];
    s2 = red[4] + red[5] + red[6] + red[7];
    const float mean = s * (1.0f / Dc);
    const float var  = s2 * (1.0f / Dc) - mean * mean;
    const float rstd = rsqrtf(var + 1e-5f);
    bf16* orow = out + (size_t)blk * Dc;
    #pragma unroll
    for (int i = 0; i < 3; i++) {
        int c = t + i * 256;
        orow[c] = f2b((v[i] - mean) * rstd * g[c] + bt[c]);
    }
}

// ---------------------------------------------------------------- GEMM (C = A @ B^T + bias, fused epilogues)
// TN = 192 (4 waves 2Mx2N of 64x96, 48 MFMA/K-step/wave): qkv ONLY -- grid
//   12x64 = 768 = exact 3/CU fill. (r12: up-proj at TN=192 gave 512 blocks
//   @ 2/CU = 2 waves/SIMD and regressed ~12us -- amortization never beats
//   a lost occupancy tier; third confirmation after r5/r9.)
// TN = 128 (4 waves of 64x64) for up-proj (grid 12x64 = 768 exact, 3/CU).
// TN = 64 (4 waves of 32x64) + BK=128 for out/down (grid 12x64 = 768 exact).
// Single-buffered __syncthreads loop; m-inner XCD stripe.
// EPI_QKV: split-store Q|K|Vt; Q pre-scaled by log2(e)/8.
enum { EPI_QKV = 0, EPI_GELU_BF16 = 1, EPI_RESID_F32 = 2, EPI_ACC_F32 = 3 };

template <int EPI, int TN, int BK>
__global__ __launch_bounds__(256, 3) void gemm_bt(
    const bf16* __restrict__ A, const bf16* __restrict__ Bw,
    const float* __restrict__ bias,
    bf16* __restrict__ Cb, float* __restrict__ Cf,
    const float* __restrict__ resf,
    int M, int N, int K, int lda, int ldb)
{
    constexpr int MI = (TN == 64) ? 2 : 4;       // 16-row blocks per wave (m)
    constexpr int NI = (TN == 192) ? 6 : 4;      // 16-col blocks per wave (n)
    constexpr int CH = BK / 8;                   // 16B chunks per tile row
    __shared__ __align__(16) bf16 sA[128 * BK];
    __shared__ __align__(16) bf16 sB[TN * BK];
    const int t = threadIdx.x, wave = t >> 6, lane = t & 63;
    const int moff = (TN == 64) ? wave * 32 : (wave & 1) * 64;
    const int noff = (TN == 64) ? 0 : (wave >> 1) * (NI * 16);
    // XCD stripe swizzle, m innermost (ny divisible by 8 for all our shapes)
    const int nx = gridDim.x, ny = gridDim.y;
    const int nym = ny >> 3;                     // m-tiles per XCD
    const int bid = blockIdx.y * nx + blockIdx.x;
    const int xcd = bid & 7, kk = bid >> 3;
    const int m0 = (xcd * nym + kk % nym) * 128;
    const int n0 = (kk / nym) * TN;
    const bf16* Ag = A + (size_t)m0 * lda;
    const bf16* Bg = Bw + (size_t)n0 * ldb;

    v4f acc[MI][NI];
    #pragma unroll
    for (int i = 0; i < MI; i++)
        #pragma unroll
        for (int j = 0; j < NI; j++) acc[i][j] = (v4f)(0.0f);

    for (int k0 = 0; k0 < K; k0 += BK) {
        // stage with XOR swizzle: LDS chunk l holds global chunk ((l&7)^(r&7))|(l&~7)
        #pragma unroll
        for (int i = 0; i < (128 * CH) / 256; i++) {
            int c = i * 256 + t;
            int r = c / CH, l0 = c % CH;
            int j = ((l0 & 7) ^ (r & 7)) | (l0 & ~7);
            GLDS(Ag + (size_t)r * lda + k0 + j * 8,
                 &sA[(i * 256 + wave * 64) * 8]);
        }
        #pragma unroll
        for (int i = 0; i < (TN * CH) / 256; i++) {
            int c = i * 256 + t;
            int r = c / CH, l0 = c % CH;
            int j = ((l0 & 7) ^ (r & 7)) | (l0 & ~7);
            GLDS(Bg + (size_t)r * ldb + k0 + j * 8,
                 &sB[(i * 256 + wave * 64) * 8]);
        }
        __syncthreads();
        #pragma unroll
        for (int ks = 0; ks < BK / 32; ks++) {
            const int rq = lane >> 4, rl = lane & 15;
            const int q = ks * 4 + rq;
            v8bf a[MI], b[NI];
            #pragma unroll
            for (int mi = 0; mi < MI; mi++) {
                const int row = moff + mi * 16 + rl;
                const int l = ((q & 7) ^ (row & 7)) | (q & ~7);
                a[mi] = *(const v8bf*)&sA[row * BK + l * 8];
            }
            #pragma unroll
            for (int ni = 0; ni < NI; ni++) {
                const int row = noff + ni * 16 + rl;
                const int l = ((q & 7) ^ (row & 7)) | (q & ~7);
                b[ni] = *(const v8bf*)&sB[row * BK + l * 8];
            }
            #pragma unroll
            for (int mi = 0; mi < MI; mi++)
                #pragma unroll
                for (int ni = 0; ni < NI; ni++)
                    acc[mi][ni] = __builtin_amdgcn_mfma_f32_16x16x32_bf16(
                        a[mi], b[ni], acc[mi][ni], 0, 0, 0);
        }
        __syncthreads();
    }

    const int rq = lane >> 4, cn = lane & 15;
    #pragma unroll
    for (int mi = 0; mi < MI; mi++)
        #pragma unroll
        for (int ni = 0; ni < NI; ni++) {
            const int col = n0 + noff + ni * 16 + cn;
            const float bv = bias ? bias[col] : 0.0f;
            if constexpr (EPI == EPI_QKV) {
                const int row0 = m0 + moff + mi * 16 + rq * 4;
                if (col < 2 * Dc) {
                    bf16* dst = Cb + (col < Dc ? 0 : (size_t)BTc * Dc);
                    const int cadj = col < Dc ? col : col - Dc;
                    const float qs = (col < Dc) ? 0.18033688011112042f : 1.0f;
                    #pragma unroll
                    for (int r = 0; r < 4; r++)
                        dst[(size_t)(row0 + r) * Dc + cadj] = f2b((acc[mi][ni][r] + bv) * qs);
                } else {
                    const int vcol = col - 2 * Dc;
                    const int hh = vcol >> 6, hd = vcol & 63;
                    const int bb = row0 >> 11, t0 = row0 & 2047;
                    v4bf pk;
                    #pragma unroll
                    for (int r = 0; r < 4; r++) pk[r] = f2b(acc[mi][ni][r] + bv);
                    *(v4bf*)(Cb + 2 * (size_t)BTc * Dc +
                             (((size_t)bb * Hc + hh) * HDc + hd) * Tc + t0) = pk;
                }
            } else {
                #pragma unroll
                for (int r = 0; r < 4; r++) {
                    const int row = m0 + moff + mi * 16 + rq * 4 + r;
                    const size_t idx = (size_t)row * N + col;
                    float vv = acc[mi][ni][r] + bv;
                    if constexpr (EPI == EPI_GELU_BF16) {
                        Cb[idx] = f2b(0.5f * vv * (1.0f + erff(vv * 0.70710678118f)));
                    } else if constexpr (EPI == EPI_RESID_F32) {
                        Cf[idx] = vv + resf[idx];
                    } else {  // EPI_ACC_F32: sequential RMW accumulate
                        Cf[idx] = vv + Cf[idx];
                    }
                }
            }
        }
}

// ---------------------------------------------------------------- Banded flash attention, v6 (KBLK=128)
// v5 core (LDS-staged K/V, 32-row q-strips, transposed-S b64 P-writes,
// l via ones-MFMA, no exp clamp) + KBLK=128 phases: stage K[128x64] +
// V[64x128] per phase (16+16KB; +sP = 48KB, still 3 blocks/CU), both
// 64-key halves between ONE barrier pair (half the vmcnt(0) drains).
__global__ __launch_bounds__(256, 3) void attn_kernel(
    const bf16* __restrict__ Qb, const bf16* __restrict__ Kb,
    const bf16* __restrict__ Vt, bf16* __restrict__ o,
    const int* __restrict__ winp)
{
    const int bh = blockIdx.x, qt = blockIdx.y;
    const int b = bh / Hc, h = bh % Hc;
    const int q0 = qt * 128;
    const int win = *winp;
    const int t = threadIdx.x, wave = t >> 6, lane = t & 63;
    const int rq = lane >> 4, cn = lane & 15;
    const int qw0 = q0 + wave * 32;              // this wave's 32-row q-strip

    __shared__ __align__(16) bf16 sK[128 * 64];  // 128 keys x 64 d
    __shared__ __align__(16) bf16 sV[64 * 128];  // 64 hd x 128 keys
    __shared__ __align__(16) bf16 sP[4][32 * 64];
    bf16* const sPw = &sP[wave][0];
    const int swz = (cn & 7) << 1;               // XOR on 8B-chunk index

    const bf16* qp  = Qb + ((size_t)b * Tc) * Dc + h * HDc;
    const bf16* kp  = Kb + ((size_t)b * Tc) * Dc + h * HDc;
    const bf16* vtp = Vt + (size_t)bh * HDc * Tc;

    // Q fragments (B-operand: col=q=cn within tile mi, k = ks*32+rq*8)
    v8bf qf[2][2];
    #pragma unroll
    for (int ks = 0; ks < 2; ks++)
        #pragma unroll
        for (int mi = 0; mi < 2; mi++)
            qf[ks][mi] = *(const v8bf*)(qp + (size_t)(qw0 + mi * 16 + cn) * Dc
                                        + ks * 32 + rq * 8);

    v4f acc_o[2][4], acc_l[2];
    #pragma unroll
    for (int mi = 0; mi < 2; mi++) {
        acc_l[mi] = (v4f)(0.0f);
        #pragma unroll
        for (int nh = 0; nh < 4; nh++) acc_o[mi][nh] = (v4f)(0.0f);
    }
    v8bf vones;
    #pragma unroll
    for (int j = 0; j < 8; j++) vones[j] = f2b(1.0f);

    // block band; per-wave valid range
    const int wlo = max(0, qw0 - win), whi = min(Tc - 1, qw0 + 31 + win);
    const int klo = max(0, q0 - win) & ~127;     // 128-aligned phase base
    const int khi = min(Tc - 1, q0 + 127 + win);

    for (int kb0 = klo; kb0 <= khi; kb0 += 128) {
        // cooperative stage: K rows [kb0..+128) x 64d (4x16B/thread),
        // V^T rows [0..64) x keys [kb0..+128) (4x16B/thread).
        // K swizzle: chunk j = (c&7)^(r&7) (8 chunks/row).
        // V swizzle: 16 chunks/row -> j = ((l&7)^(r&7))|(l&8) (bit 3 kept).
        #pragma unroll
        for (int i = 0; i < 4; i++) {
            int c = i * 256 + t;
            int rk = c >> 3, jk = (c & 7) ^ (rk & 7);
            GLDS(kp + (size_t)(kb0 + rk) * Dc + jk * 8,
                 &sK[(i * 256 + wave * 64) * 8]);
            int rv = c >> 4, lv = c & 15;
            int jv = ((lv & 7) ^ (rv & 7)) | (lv & 8);
            GLDS(vtp + (size_t)rv * Tc + kb0 + jv * 8,
                 &sV[(i * 256 + wave * 64) * 8]);
        }
        __syncthreads();

        #pragma unroll
        for (int half = 0; half < 2; half++) {
            const int kb = kb0 + half * 64;
            if (kb + 63 >= wlo && kb <= whi) {
                // S^T = K Q^T : sf[k4][mi], row k = kb+k4*16+rq*4+r, col q = mi*16+cn
                v4f sf[4][2];
                #pragma unroll
                for (int k4 = 0; k4 < 4; k4++)
                    #pragma unroll
                    for (int mi = 0; mi < 2; mi++) sf[k4][mi] = (v4f)(0.0f);
                #pragma unroll
                for (int ks = 0; ks < 2; ks++) {
                    v8bf kf[4];
                    #pragma unroll
                    for (int k4 = 0; k4 < 4; k4++) {
                        const int row = half * 64 + k4 * 16 + cn;
                        kf[k4] = *(const v8bf*)&sK[row * 64
                                                  + ((ks * 4 + rq) ^ (row & 7)) * 8];
                    }
                    #pragma unroll
                    for (int k4 = 0; k4 < 4; k4++)
                        #pragma unroll
                        for (int mi = 0; mi < 2; mi++)
                            sf[k4][mi] = __builtin_amdgcn_mfma_f32_16x16x32_bf16(
                                kf[k4], qf[ks][mi], sf[k4][mi], 0, 0, 0);
                }

                // p = exp2(sT); band mask only on edge halves
                const bool need_mask = (kb + 63 - qw0 > win) || (qw0 + 31 - kb > win);
                #pragma unroll
                for (int k4 = 0; k4 < 4; k4++)
                    #pragma unroll
                    for (int mi = 0; mi < 2; mi++) {
                        v4bf pk;
                        #pragma unroll
                        for (int r = 0; r < 4; r++) {
                            float tt = sf[k4][mi][r];
                            if (need_mask) {
                                int ki = kb + k4 * 16 + rq * 4 + r;
                                int qi = qw0 + mi * 16 + cn;
                                int dd = qi - ki; dd = dd < 0 ? -dd : dd;
                                tt = (dd > win) ? -INFINITY : tt;
                            }
                            pk[r] = f2b(exp2f(tt));   // masked -> 0
                        }
                        *(v4bf*)&sPw[(mi * 16 + cn) * 64
                                     + (((k4 * 4 + rq) ^ swz) << 2)] = pk;
                    }

                // O += P V ; l += P 1  (A: row q = mi*16+cn; B from sV / ones)
                #pragma unroll
                for (int ks = 0; ks < 2; ks++) {
                    v8bf pa[2], vf[4];
                    #pragma unroll
                    for (int mi = 0; mi < 2; mi++)
                        pa[mi] = *(const v8bf*)&sPw[(mi * 16 + cn) * 64
                                                    + (((ks * 8 + rq * 2) ^ swz) << 2)];
                    #pragma unroll
                    for (int nh = 0; nh < 4; nh++) {
                        const int row = nh * 16 + cn;
                        const int lv = half * 8 + ks * 4 + rq;
                        const int jv = ((lv & 7) ^ (row & 7)) | (lv & 8);
                        vf[nh] = *(const v8bf*)&sV[row * 128 + jv * 8];
                    }
                    #pragma unroll
                    for (int mi = 0; mi < 2; mi++)
                        acc_l[mi] = __builtin_amdgcn_mfma_f32_16x16x32_bf16(
                            pa[mi], vones, acc_l[mi], 0, 0, 0);
                    #pragma unroll
                    for (int mi = 0; mi < 2; mi++)
                        #pragma unroll
                        for (int nh = 0; nh < 4; nh++)
                            acc_o[mi][nh] = __builtin_amdgcn_mfma_f32_16x16x32_bf16(
                                pa[mi], vf[nh], acc_o[mi][nh], 0, 0, 0);
                }
            }
        }
        __syncthreads();
    }

    // epilogue: normalize + store; l for row rq*4+r is acc_l[mi][r]
    bf16* ob = o + ((size_t)b * Tc + qw0) * Dc + h * HDc;
    #pragma unroll
    for (int mi = 0; mi < 2; mi++)
        #pragma unroll
        for (int r = 0; r < 4; r++) {
            const float invl = 1.0f / acc_l[mi][r];  // diag in band -> l > 0
            #pragma unroll
            for (int nh = 0; nh < 4; nh++)
                ob[(size_t)(mi * 16 + rq * 4 + r) * Dc + nh * 16 + cn] =
                    f2b(acc_o[mi][nh][r] * invl);
        }
}

// ---------------------------------------------------------------- launch
extern "C" void kernel_launch(void* const* d_in, const int* in_sizes, int n_in,
                              void* d_out, int out_size, void* d_ws, size_t ws_size,
                              hipStream_t stream)
{
    const float* x     = (const float*)d_in[0];
    const float* inw   = (const float*)d_in[1];
    const float* inb   = (const float*)d_in[2];
    const float* outw  = (const float*)d_in[3];
    const float* outb  = (const float*)d_in[4];
    const float* w1    = (const float*)d_in[5];
    const float* b1    = (const float*)d_in[6];
    const float* w2    = (const float*)d_in[7];
    const float* b2    = (const float*)d_in[8];
    const float* ln1g  = (const float*)d_in[9];
    const float* ln1b  = (const float*)d_in[10];
    const float* ln2g  = (const float*)d_in[11];
    const float* ln2b  = (const float*)d_in[12];
    const int*   winp  = (const int*)d_in[13];
    float* out = (float*)d_out;   // fp32 [8192][768]; holds x1 mid-pipeline

    // Workspace (55.05 MB needed; >=62.9 MB proven available)
    char* ws = (char*)d_ws;
    constexpr size_t A_OFF   = 0;
    constexpr size_t QKV_OFF = (size_t)BTc * Dc * 2;                   // 12582912
    constexpr size_t WA_OFF  = QKV_OFF + 3 * (size_t)BTc * Dc * 2;     // 50331648
    constexpr size_t WS_NEED = WA_OFF + (size_t)(QKVc + Dc) * Dc * 2;  // 55050240
    if (ws_size < WS_NEED) return;

    bf16*  xn     = (bf16*)(ws + A_OFF);            // xn1 / obuf / xn2
    bf16*  qkvb   = (bf16*)(ws + QKV_OFF);          // Qb|Kb|Vt triple
    bf16*  Qb     = qkvb;
    bf16*  Kb     = qkvb + (size_t)BTc * Dc;
    bf16*  Vt     = qkvb + 2 * (size_t)BTc * Dc;
    bf16*  hbuf   = (bf16*)(ws + QKV_OFF);          // phase B: [8192][1536] bf16
    bf16*  wmlp   = (bf16*)(ws + QKV_OFF + (size_t)BTc * (2 * Dc) * 2);
    bf16*  w1_b   = wmlp;
    bf16*  w2_b   = wmlp + (size_t)MLPc * Dc;
    bf16*  wqkv_b = (bf16*)(ws + WA_OFF);
    bf16*  wout_b = wqkv_b + (size_t)QKVc * Dc;

    constexpr int HALF = MLPc / 2;  // 1536 cols per MLP half (N-split)
    constexpr int NQKV4 = QKVc * Dc / 4, NOUT4 = Dc * Dc / 4;
    constexpr int NW14  = MLPc * Dc / 4, NW24  = Dc * MLPc / 4;
    constexpr int CVA_BLKS = (NQKV4 + NOUT4) / 256;  // 2304
    constexpr int CVB_BLKS = (NW14 + NW24) / 256;    // 4608

    // 1. LN1 (fp32 x -> bf16 xn) + folded phase-A weight conversion
    ln_kernel<<<BTc + CVA_BLKS, 256, 0, stream>>>(
        x, ln1g, ln1b, xn, inw, wqkv_b, NQKV4, outw, wout_b);
    // 2. qkv GEMM, TN=192: grid 12x64 = 768 = exact 3/CU fill
    gemm_bt<EPI_QKV, 192, 64><<<dim3(QKVc / 192, BTc / 128), 256, 0, stream>>>(
        xn, wqkv_b, inb, qkvb, nullptr, nullptr, BTc, QKVc, Dc, Dc, Dc);
    // 3. banded attention (KBLK=128 phases) -> obuf (= xn)
    attn_kernel<<<dim3(Bc * Hc, Tc / 128), 256, 0, stream>>>(Qb, Kb, Vt, xn, winp);
    // 4. out(x1) = x + obuf @ out_w^T + out_b  (fp32, fused residual; BK=128;
    //    grid 12x64 = 768 blocks = exact 3/CU fill)
    gemm_bt<EPI_RESID_F32, 64, 128><<<dim3(Dc / 64, BTc / 128), 256, 0, stream>>>(
        xn, wout_b, outb, nullptr, out, x, BTc, Dc, Dc, Dc, Dc);
    // 5. LN2 (d_out fp32 -> bf16 xn2) + folded phase-B weight conversion
    ln_kernel<<<BTc + CVB_BLKS, 256, 0, stream>>>(
        out, ln2g, ln2b, xn, w1, w1_b, NW14, w2, w2_b);

    // 6/7. MLP in two 1536-wide N-halves (every dispatch 768 blocks = exact
    // 3/CU fill). Up: TN=128/BK=64 (r11 proven). Down: K=1536, BK=128,
    // sequential RMW accumulate onto d_out.
    for (int c = 0; c < 2; c++) {
        const bf16* w1c = w1_b + (size_t)c * HALF * Dc;   // rows [c*1536, ..)
        const bf16* w2c = w2_b + (size_t)c * HALF;        // cols [c*1536, ..)
        gemm_bt<EPI_GELU_BF16, 128, 64><<<dim3(HALF / 128, BTc / 128), 256, 0, stream>>>(
            xn, w1c, b1 + c * HALF, hbuf, nullptr, nullptr, BTc, HALF, Dc, Dc, Dc);
        gemm_bt<EPI_ACC_F32, 64, 128><<<dim3(Dc / 64, BTc / 128), 256, 0, stream>>>(
            hbuf, w2c, (c == 0) ? b2 : nullptr, nullptr, out, nullptr,
            BTc, Dc, HALF, HALF, MLPc);
    }
}